// Round 5
// baseline (93.006 us; speedup 1.0000x reference)
//
#include <hip/hip_runtime.h>
#include <hip/hip_bf16.h>
#include <math.h>

#define L_SEQ 1024
#define DIMSZ 512
#define NH 8
#define ND 64
#define NB 2
#define CHUNK 64
#define NC (L_SEQ / CHUNK)   // 16
#define BHTOT (NB * NH)      // 16
#define MTOT 2048
#define NTOT 1536
#define KEFF 1536
#define BM 128
#define BN 96

typedef __attribute__((ext_vector_type(8))) short bf16x8;
typedef __attribute__((ext_vector_type(4))) float f32x4;

#define GLD16(g, l) __builtin_amdgcn_global_load_lds( \
    (const __attribute__((address_space(1))) unsigned int*)(g), \
    (__attribute__((address_space(3))) unsigned int*)(l), 16, 0, 0)

__device__ static inline unsigned short bf16_hi(float f) {
    union { float f; unsigned u; } x; x.f = f;
    unsigned lsb = (x.u >> 16) & 1u;
    unsigned rounded = x.u + 0x7fffu + lsb;
    return (unsigned short)(rounded >> 16);
}
__device__ static inline float bf16_f(unsigned short h) {
    union { float f; unsigned u; } x; x.u = ((unsigned)h) << 16;
    return x.f;
}

// ---------------------------------------------------------------------------
// pack_all: [0,1024)   A' = [x_hi | x_lo | x_hi]
//           [1024,1792) B' = [W_hi | W_hi | W_lo]
//           [1792,3840) rot[l][hd] = e^{i*theta_hd*l}
//           3840        ampow[h][p] = sigmoid(amp_h)^p, p=0..64  (520 entries!)
// ---------------------------------------------------------------------------
__global__ __launch_bounds__(256) void pack_all_kernel(
    const float* __restrict__ x,
    const float* __restrict__ wq, const float* __restrict__ wk, const float* __restrict__ wv,
    const float* __restrict__ ph_re, const float* __restrict__ ph_im,
    const float* __restrict__ amplitude,
    unsigned short* __restrict__ A, unsigned short* __restrict__ Bm,
    float2* __restrict__ rot, float* __restrict__ ampow)
{
    const int bid = blockIdx.x;
    const int tid = threadIdx.x;
    if (bid < 1024) {
        const int i = bid * 256 + tid;
        const int n  = i >> 7;
        const int kq = (i & 127) << 2;
        const float4 xv = *(const float4*)(x + (size_t)n * DIMSZ + kq);
        const float fa[4] = {xv.x, xv.y, xv.z, xv.w};
        unsigned short hv[4], lv[4];
        #pragma unroll
        for (int j = 0; j < 4; ++j) {
            hv[j] = bf16_hi(fa[j]);
            lv[j] = bf16_hi(fa[j] - bf16_f(hv[j]));
        }
        unsigned short* row = A + (size_t)n * KEFF;
        *(ushort4*)(row + kq)        = make_ushort4(hv[0], hv[1], hv[2], hv[3]);
        *(ushort4*)(row + 512 + kq)  = make_ushort4(lv[0], lv[1], lv[2], lv[3]);
        *(ushort4*)(row + 1024 + kq) = make_ushort4(hv[0], hv[1], hv[2], hv[3]);
    } else if (bid < 1792) {
        const int idx = bid - 1024;
        const int which = idx >> 8;
        const float* w = which == 0 ? wq : (which == 1 ? wk : wv);
        const int i = (idx & 255) * 256 + tid;
        const int o  = i >> 7;
        const int kq = (i & 127) << 2;
        const float4 wv4 = *(const float4*)(w + (size_t)o * DIMSZ + kq);
        const float fa[4] = {wv4.x, wv4.y, wv4.z, wv4.w};
        unsigned short hv[4], lv[4];
        #pragma unroll
        for (int j = 0; j < 4; ++j) {
            hv[j] = bf16_hi(fa[j]);
            lv[j] = bf16_hi(fa[j] - bf16_f(hv[j]));
        }
        unsigned short* row = Bm + (size_t)(which * 512 + o) * KEFF;
        *(ushort4*)(row + kq)        = make_ushort4(hv[0], hv[1], hv[2], hv[3]);
        *(ushort4*)(row + 512 + kq)  = make_ushort4(hv[0], hv[1], hv[2], hv[3]);
        *(ushort4*)(row + 1024 + kq) = make_ushort4(lv[0], lv[1], lv[2], lv[3]);
    } else if (bid < 3840) {
        const int i = (bid - 1792) * 256 + tid;   // 0..524287
        const int l  = i >> 9;
        const int hd = i & 511;
        const float th = atan2f(ph_im[hd], ph_re[hd]);
        float s, c; sincosf(th * (float)l, &s, &c);
        rot[i] = make_float2(c, s);
    } else {
        // FIX(R5): 520 entries > 256 threads -> strided loop (R4 left 256..519
        // unwritten = ws poison => heads h>=4 got ~zero amp powers).
        for (int t0 = tid; t0 < NH * 65; t0 += 256) {
            const int h = t0 / 65;
            const int p = t0 - h * 65;
            const float a = amplitude[h];
            const float amp = 1.0f / (1.0f + expf(-a));
            ampow[t0] = expf(logf(amp) * (float)p);
        }
    }
}

// ---------------------------------------------------------------------------
// GEMM: C[2048 x 1536] = A' x B'^T, MFMA 16x16x32 bf16, 128x96 tile.
// Epilogue applies the position rotation: writes qrot/krot (float2) and v.
// ---------------------------------------------------------------------------
__global__ __launch_bounds__(256) void gemm_kernel(
    const unsigned short* __restrict__ A, const unsigned short* __restrict__ Bm,
    const float* __restrict__ bq, const float* __restrict__ bk, const float* __restrict__ bv,
    const float2* __restrict__ rot,
    float2* __restrict__ qrot, float2* __restrict__ krot, float* __restrict__ vo)
{
    __shared__ __align__(16) char lds[2][28672];   // [A 16KB | B 12KB] x 2
    const int tid  = threadIdx.x;
    const int lane = tid & 63;
    const int wave = tid >> 6;

    const int bid = blockIdx.y * 16 + blockIdx.x;
    const int sw  = (bid & 7) * 32 + (bid >> 3);
    const int row0 = (sw >> 4) * BM;
    const int col0 = (sw & 15) * BN;
    const int wr = wave >> 1, wc = wave & 1;

    const int srow = tid >> 3;
    const int sin  = (tid & 7) << 4;
    size_t goffA[4], goffB[3];
    #pragma unroll
    for (int c = 0; c < 4; ++c) {
        const int row = c * 32 + srow;
        const int swz = sin ^ ((row & 7) << 4);
        goffA[c] = (size_t)(row0 + row) * (KEFF * 2) + swz;
    }
    #pragma unroll
    for (int c = 0; c < 3; ++c) {
        const int row = c * 32 + srow;
        const int swz = sin ^ ((row & 7) << 4);
        goffB[c] = (size_t)(col0 + row) * (KEFF * 2) + swz;
    }
    const int ldst = tid * 16;
    const char* Abyte = (const char*)A;
    const char* Bbyte = (const char*)Bm;

    f32x4 acc[4][3];
    const f32x4 zf = {0.f, 0.f, 0.f, 0.f};
    #pragma unroll
    for (int m = 0; m < 4; ++m)
        #pragma unroll
        for (int n = 0; n < 3; ++n) acc[m][n] = zf;

    auto stage = [&](int buf, int t) {
        char* la = &lds[buf][0];
        char* lb = &lds[buf][16384];
        const size_t kb = (size_t)t * 128;
        #pragma unroll
        for (int c = 0; c < 4; ++c)
            GLD16(Abyte + goffA[c] + kb, la + c * 4096 + ldst);
        #pragma unroll
        for (int c = 0; c < 3; ++c)
            GLD16(Bbyte + goffB[c] + kb, lb + c * 4096 + ldst);
    };

    const int rl = lane & 15;
    const int kg = lane >> 4;
    const int rswz = (rl & 7) << 4;

    auto compute = [&](int buf) {
        const char* la = &lds[buf][0];
        const char* lb = &lds[buf][16384];
        #pragma unroll
        for (int ks = 0; ks < 2; ++ks) {
            bf16x8 av[4], bvv[3];
            #pragma unroll
            for (int m = 0; m < 4; ++m) {
                const int row = wr * 64 + m * 16 + rl;
                const int addr = (row * 128 + ks * 64 + kg * 16) ^ rswz;
                av[m] = *(const bf16x8*)(la + addr);
            }
            #pragma unroll
            for (int n = 0; n < 3; ++n) {
                const int row = wc * 48 + n * 16 + rl;
                const int addr = (row * 128 + ks * 64 + kg * 16) ^ rswz;
                bvv[n] = *(const bf16x8*)(lb + addr);
            }
            #pragma unroll
            for (int m = 0; m < 4; ++m)
                #pragma unroll
                for (int n = 0; n < 3; ++n)
                    acc[m][n] = __builtin_amdgcn_mfma_f32_16x16x32_bf16(
                        av[m], bvv[n], acc[m][n], 0, 0, 0);
        }
    };

    stage(0, 0);
    __syncthreads();
    const int NT = KEFF / 64;   // 24
    for (int t = 0; t < NT; ++t) {
        if (t + 1 < NT) stage((t + 1) & 1, t + 1);
        compute(t & 1);
        __syncthreads();
    }

    // --- epilogue: bias + rotation + store ---
    #pragma unroll
    for (int n = 0; n < 3; ++n) {
        const int cabs = col0 + wc * 48 + n * 16 + rl;
        const int which = cabs >> 9;        // wave-uniform (16-col frag aligned)
        const int cl = cabs & 511;
        const float* bias = which == 0 ? bq : (which == 1 ? bk : bv);
        const float bs = bias[cl];
        #pragma unroll
        for (int m = 0; m < 4; ++m) {
            const int rb = row0 + wr * 64 + m * 16 + kg * 4;
            #pragma unroll
            for (int r = 0; r < 4; ++r) {
                const int row = rb + r;
                const float val = acc[m][n][r] + bs;
                const size_t oo = (size_t)row * DIMSZ + cl;
                if (which == 2) {
                    vo[oo] = val;
                } else {
                    const float2 rt = rot[(size_t)(row & (L_SEQ - 1)) * DIMSZ + cl];
                    if (which == 0) qrot[oo] = make_float2(val * rt.x,  val * rt.y);
                    else            krot[oo] = make_float2(val * rt.x, -val * rt.y);
                }
            }
        }
    }
}

// ---------------------------------------------------------------------------
// chunk_kv: KV_c[d,e] = sum_j amp^{63-j} ktilde[j,d] v[j,e]   (complex x real)
// ---------------------------------------------------------------------------
__global__ __launch_bounds__(256) void chunk_kv_kernel(
    const float2* __restrict__ krot, const float* __restrict__ v,
    const float* __restrict__ ampow, float2* __restrict__ kv)
{
    const int bhc = blockIdx.x;
    const int c  = bhc & (NC - 1);
    const int bh = bhc >> 4;
    const int b = bh >> 3, h = bh & 7;
    const int tid = threadIdx.x;
    const int lane = tid & 63, grp = tid >> 6;

    __shared__ float ktr[CHUNK][ND + 1];
    __shared__ float kti[CHUNK][ND + 1];
    __shared__ float vs[CHUNK][ND + 1];

    for (int jj = 0; jj < 16; ++jj) {
        const int j = grp*16 + jj;
        const int l = c*CHUNK + j;
        const size_t off = ((size_t)(b*L_SEQ + l)) * DIMSZ + h*ND + lane;
        const float2 kf = krot[off];
        const float ap = ampow[h*65 + (CHUNK - 1 - j)];
        ktr[j][lane] = kf.x * ap;
        kti[j][lane] = kf.y * ap;
        vs[j][lane]  = v[off];
    }
    __syncthreads();

    float accr[16], acci[16];
    #pragma unroll
    for (int dd = 0; dd < 16; ++dd) { accr[dd] = 0.f; acci[dd] = 0.f; }
    for (int j = 0; j < CHUNK; ++j) {
        const float vv = vs[j][lane];
        #pragma unroll
        for (int dd = 0; dd < 16; ++dd) {
            const int d = grp*16 + dd;
            accr[dd] = fmaf(ktr[j][d], vv, accr[dd]);
            acci[dd] = fmaf(kti[j][d], vv, acci[dd]);
        }
    }
    float2* dst = kv + (size_t)bhc * (ND*ND);
    #pragma unroll
    for (int dd = 0; dd < 16; ++dd) {
        const int d = grp*16 + dd;
        dst[d*ND + lane] = make_float2(accr[dd], acci[dd]);
    }
}

// ---------------------------------------------------------------------------
// scan: B_{c+1} = amp^64 * B_c + KV_c (REAL decay), B_0 = e^{i theta_d} * lc.
// kvB[bhc] := state BEFORE chunk c.
// ---------------------------------------------------------------------------
__global__ __launch_bounds__(256) void scan_kernel(
    float2* __restrict__ kvB,
    const float* __restrict__ lc_re, const float* __restrict__ lc_im,
    const float2* __restrict__ rot, const float* __restrict__ ampow)
{
    const int gid = blockIdx.x * 256 + threadIdx.x;   // 65536
    const int bh = gid >> 12;
    const int idx = gid & 4095;
    const int h = bh & 7;
    const int d = idx >> 6;

    const float aC = ampow[h*65 + CHUNK];             // amp^64 (real)
    const float2 r1 = rot[(size_t)DIMSZ + h*ND + d];  // e^{i theta_d}  (l=1)

    const float lr = lc_re[h*ND*ND + idx];
    const float li = lc_im[h*ND*ND + idx];
    float Sr = r1.x * lr - r1.y * li;
    float Si = r1.x * li + r1.y * lr;

    float2* base = kvB + (size_t)bh * NC * (ND*ND) + idx;
    float2 t[NC];
    #pragma unroll
    for (int c = 0; c < NC; ++c) t[c] = base[(size_t)c * (ND*ND)];
    #pragma unroll
    for (int c = 0; c < NC; ++c) {
        base[(size_t)c * (ND*ND)] = make_float2(Sr, Si);
        Sr = aC * Sr + t[c].x;
        Si = aC * Si + t[c].y;
    }
}

// ---------------------------------------------------------------------------
// chunk_out: 512 blocks (bhc*2+half), 32 output rows each.
//  scores = QR.KR^T - QI.KI^T, masked by amp^delta; PV; then
//  cross = (QR.BR - QI.BI) * amp^{j+1}, with B staged through LDS (KI/VS reuse).
// ---------------------------------------------------------------------------
__global__ __launch_bounds__(256) void chunk_out_kernel(
    const float2* __restrict__ qrot, const float2* __restrict__ krot,
    const float* __restrict__ v, const float2* __restrict__ Bst,
    const float* __restrict__ ampow, float* __restrict__ out)
{
    const int half = blockIdx.x & 1;
    const int bhc = blockIdx.x >> 1;
    const int c  = bhc & (NC - 1);
    const int bh = bhc >> 4;
    const int b = bh >> 3, h = bh & 7;
    const int tid = threadIdx.x;
    const int lane = tid & 63, grp = tid >> 6;
    const int ty = tid >> 4, tx = tid & 15;   // 2 rows x 4 cols per thread

    __shared__ float QR[32][ND + 1];
    __shared__ float QI[32][ND + 1];
    __shared__ float KR[CHUNK][ND + 1];   // later rows 0..31 reused for SA
    __shared__ float KI[CHUNK][ND + 1];   // later reused for BR
    __shared__ float VS[CHUNK][ND + 1];   // later reused for BI
    __shared__ float apw[72];

    // early B-tile loads into registers (latency hidden under scores/PV)
    float2 breg[16];
    const float2* Bbase = Bst + (size_t)bhc * (ND*ND);
    #pragma unroll
    for (int ii = 0; ii < 16; ++ii) breg[ii] = Bbase[tid * 16 + ii];

    if (tid < 65) apw[tid] = ampow[h*65 + tid];
    {
        #pragma unroll
        for (int jj = 0; jj < 8; ++jj) {
            const int jl = grp*8 + jj;
            const int jabs = half*32 + jl;
            const int l = c*CHUNK + jabs;
            const size_t off = ((size_t)(b*L_SEQ + l)) * DIMSZ + h*ND + lane;
            const float2 qf = qrot[off];
            QR[jl][lane] = qf.x; QI[jl][lane] = qf.y;
        }
        #pragma unroll
        for (int jj = 0; jj < 16; ++jj) {
            const int j = grp*16 + jj;
            const int l = c*CHUNK + j;
            const size_t off = ((size_t)(b*L_SEQ + l)) * DIMSZ + h*ND + lane;
            const float2 kf = krot[off];
            KR[j][lane] = kf.x; KI[j][lane] = kf.y;
            VS[j][lane] = v[off];
        }
    }
    __syncthreads();

    // ---- intra scores A[jl, jp] = Re(q~ . k~) ----
    float accA[2][4] = {};
    for (int d = 0; d < ND; ++d) {
        float qrv[2], qiv[2], krv[4], kiv[4];
        #pragma unroll
        for (int i = 0; i < 2; ++i) { qrv[i] = QR[ty*2+i][d]; qiv[i] = QI[ty*2+i][d]; }
        #pragma unroll
        for (int u = 0; u < 4; ++u) { krv[u] = KR[tx*4+u][d]; kiv[u] = KI[tx*4+u][d]; }
        #pragma unroll
        for (int i = 0; i < 2; ++i)
            #pragma unroll
            for (int u = 0; u < 4; ++u)
                accA[i][u] = fmaf(qrv[i], krv[u], fmaf(-qiv[i], kiv[u], accA[i][u]));
    }
    __syncthreads();

    float (*SA)[ND + 1] = KR;   // rows 0..31
    #pragma unroll
    for (int i = 0; i < 2; ++i) {
        const int jl = ty*2 + i;
        const int jabs = half*32 + jl;
        #pragma unroll
        for (int u = 0; u < 4; ++u) {
            const int jp = tx*4 + u;
            const int delta = jabs - jp;
            SA[jl][jp] = (delta >= 0) ? accA[i][u] * apw[delta] : 0.0f;
        }
    }
    __syncthreads();

    // ---- PV ----
    float accO[2][4] = {};
    const int jpmax = half*32 + 32;
    for (int jp = 0; jp < jpmax; ++jp) {
        float av[2], vv[4];
        #pragma unroll
        for (int i = 0; i < 2; ++i) av[i] = SA[ty*2+i][jp];
        #pragma unroll
        for (int u = 0; u < 4; ++u) vv[u] = VS[jp][tx*4+u];
        #pragma unroll
        for (int i = 0; i < 2; ++i)
            #pragma unroll
            for (int u = 0; u < 4; ++u)
                accO[i][u] = fmaf(av[i], vv[u], accO[i][u]);
    }
    __syncthreads();

    // ---- stage B into LDS: BR -> KI, BI -> VS ----
    #pragma unroll
    for (int ii = 0; ii < 16; ++ii) {
        const int id2 = tid * 16 + ii;
        const int d = id2 >> 6, e = id2 & 63;
        KI[d][e] = breg[ii].x;
        VS[d][e] = breg[ii].y;
    }
    __syncthreads();

    // ---- cross: accC = QR.BR - QI.BI ----
    float accC[2][4] = {};
    for (int d = 0; d < ND; ++d) {
        float qrv[2], qiv[2], brv[4], biv[4];
        #pragma unroll
        for (int i = 0; i < 2; ++i) { qrv[i] = QR[ty*2+i][d]; qiv[i] = QI[ty*2+i][d]; }
        #pragma unroll
        for (int u = 0; u < 4; ++u) { brv[u] = KI[d][tx*4+u]; biv[u] = VS[d][tx*4+u]; }
        #pragma unroll
        for (int i = 0; i < 2; ++i)
            #pragma unroll
            for (int u = 0; u < 4; ++u)
                accC[i][u] = fmaf(qrv[i], brv[u], fmaf(-qiv[i], biv[u], accC[i][u]));
    }

    #pragma unroll
    for (int i = 0; i < 2; ++i) {
        const int jabs = half*32 + ty*2 + i;
        const float cs = apw[jabs + 1];
        const int l = c*CHUNK + jabs;
        const size_t off = ((size_t)(b*L_SEQ + l)) * DIMSZ + h*ND + tx*4;
        *(float4*)(out + off) = make_float4(
            fmaf(cs, accC[i][0], accO[i][0]), fmaf(cs, accC[i][1], accO[i][1]),
            fmaf(cs, accC[i][2], accO[i][2]), fmaf(cs, accC[i][3], accO[i][3]));
    }
}

// ---------------------------------------------------------------------------
extern "C" void kernel_launch(void* const* d_in, const int* in_sizes, int n_in,
                              void* d_out, int out_size, void* d_ws, size_t ws_size,
                              hipStream_t stream)
{
    const float* x     = (const float*)d_in[0];
    const float* wq_b  = (const float*)d_in[2];
    const float* wk_b  = (const float*)d_in[4];
    const float* wv_b  = (const float*)d_in[6];
    const float* ph_re = (const float*)d_in[7];
    const float* ph_im = (const float*)d_in[8];
    const float* ampl  = (const float*)d_in[9];
    const float* lc_re = (const float*)d_in[10];
    const float* lc_im = (const float*)d_in[11];
    float* out = (float*)d_out;

    char* wsb = (char*)d_ws;
    const size_t MB = 1024 * 1024;
    float2* qrot = (float2*)(wsb + 0);          //  8 MB
    float2* krot = (float2*)(wsb + 8 * MB);     //  8 MB
    float*  vbuf = (float*)(wsb + 16 * MB);     //  4 MB
    float2* rot  = (float2*)(wsb + 20 * MB);    //  4 MB
    float*  ampow= (float*)(wsb + 24 * MB);     //  ~2 KB
    unsigned short* Apk = (unsigned short*)(wsb + 25 * MB);  // 6 MB
    unsigned short* Bpk = (unsigned short*)(wsb + 32 * MB);  // 4.5 MB
    float2* kvB  = (float2*)(wsb + 40 * MB);    //  8 MB

    pack_all_kernel<<<3841, 256, 0, stream>>>(
        x, (const float*)d_in[1], (const float*)d_in[3], (const float*)d_in[5],
        ph_re, ph_im, ampl, Apk, Bpk, rot, ampow);
    gemm_kernel<<<dim3(MTOT / BM, NTOT / BN), 256, 0, stream>>>(
        Apk, Bpk, wq_b, wk_b, wv_b, rot, qrot, krot, vbuf);
    chunk_kv_kernel<<<BHTOT * NC, 256, 0, stream>>>(krot, vbuf, ampow, kvB);
    scan_kernel<<<(BHTOT * ND * ND) / 256, 256, 0, stream>>>(kvB, lc_re, lc_im, rot, ampow);
    chunk_out_kernel<<<BHTOT * NC * 2, 256, 0, stream>>>(qrot, krot, vbuf, kvB, ampow, out);
}

// Round 6
// 76.663 us; speedup vs baseline: 1.2132x; 1.2132x over previous
//
#include <hip/hip_runtime.h>
#include <hip/hip_bf16.h>
#include <math.h>

#define L_SEQ 1024
#define DIMSZ 512
#define NH 8
#define ND 64
#define NB 2
#define CHUNK 64
#define NC (L_SEQ / CHUNK)   // 16
#define BHTOT (NB * NH)      // 16
#define MTOT 2048
#define NTOT 1536
#define KEFF 512
#define BM 64
#define BN 96

typedef __attribute__((ext_vector_type(8))) _Float16 f16x8;
typedef __attribute__((ext_vector_type(4))) float f32x4;

#define GLD16(g, l) __builtin_amdgcn_global_load_lds( \
    (const __attribute__((address_space(1))) unsigned int*)(g), \
    (__attribute__((address_space(3))) unsigned int*)(l), 16, 0, 0)

__device__ static inline unsigned short f2h(float f) {
    union { _Float16 h; unsigned short u; } x;
    x.h = (_Float16)f;
    return x.u;
}

// ---------------------------------------------------------------------------
// pack_all: [0,1024)   A[n][k] = fp16(x)          (2048 x 512)
//           [1024,1792) B[which*512+o][k] = fp16(W) (1536 x 512)
//           1792        theta[h,d], logamp[h]
// ---------------------------------------------------------------------------
__global__ __launch_bounds__(256) void pack_all_kernel(
    const float* __restrict__ x,
    const float* __restrict__ wq, const float* __restrict__ wk, const float* __restrict__ wv,
    const float* __restrict__ ph_re, const float* __restrict__ ph_im,
    const float* __restrict__ amplitude,
    unsigned short* __restrict__ A, unsigned short* __restrict__ Bm,
    float* __restrict__ theta, float* __restrict__ logamp)
{
    const int bid = blockIdx.x;
    const int tid = threadIdx.x;
    if (bid < 1024) {
        const int i = bid * 256 + tid;
        const int n  = i >> 7;
        const int kq = (i & 127) << 2;
        const float4 xv = *(const float4*)(x + (size_t)n * DIMSZ + kq);
        *(ushort4*)(A + (size_t)n * KEFF + kq) =
            make_ushort4(f2h(xv.x), f2h(xv.y), f2h(xv.z), f2h(xv.w));
    } else if (bid < 1792) {
        const int idx = bid - 1024;
        const int which = idx >> 8;
        const float* w = which == 0 ? wq : (which == 1 ? wk : wv);
        const int i = (idx & 255) * 256 + tid;
        const int o  = i >> 7;
        const int kq = (i & 127) << 2;
        const float4 wv4 = *(const float4*)(w + (size_t)o * DIMSZ + kq);
        *(ushort4*)(Bm + (size_t)(which * 512 + o) * KEFF + kq) =
            make_ushort4(f2h(wv4.x), f2h(wv4.y), f2h(wv4.z), f2h(wv4.w));
    } else {
        for (int t0 = tid; t0 < NH * ND; t0 += 256)
            theta[t0] = atan2f(ph_im[t0], ph_re[t0]);
        if (tid < NH) {
            float a = amplitude[tid];
            float amp = 1.0f / (1.0f + expf(-a));
            logamp[tid] = logf(amp);
        }
    }
}

// ---------------------------------------------------------------------------
// GEMM: C[2048 x 1536] = A x B^T, MFMA 16x16x32 f16, K=512.
// 64x96 tile, BK=64, 4 waves (2x2, wave tile 32x48), grid 32x16=512 blocks
// (2 blocks/CU for wave-overlap), double-buffered global_load_lds with
// both-sides XOR swizzle. Epilogue: bias + fp32 store to q/k/v.
// ---------------------------------------------------------------------------
__global__ __launch_bounds__(256) void gemm_kernel(
    const unsigned short* __restrict__ A, const unsigned short* __restrict__ Bm,
    const float* __restrict__ bq, const float* __restrict__ bk, const float* __restrict__ bv,
    float* __restrict__ qo, float* __restrict__ ko, float* __restrict__ vo)
{
    __shared__ __align__(16) char lds[2][20480];   // [A 8KB | B 12KB] x 2
    const int tid  = threadIdx.x;
    const int lane = tid & 63;
    const int wave = tid >> 6;

    // XCD-aware swizzle: 512 blocks / 8 XCDs = 64 consecutive sw per XCD,
    // walking M fastest (A-panel L2 reuse within an XCD).
    const int bid = blockIdx.y * 32 + blockIdx.x;
    const int sw  = (bid & 7) * 64 + (bid >> 3);
    const int row0 = (sw >> 4) * BM;     // 32 M-tiles
    const int col0 = (sw & 15) * BN;     // 16 N-tiles
    const int wr = wave >> 1, wc = wave & 1;

    const int srow = tid >> 3;                // 0..31
    const int sin  = (tid & 7) << 4;          // byte within 128B row
    size_t goffA[2], goffB[3];
    #pragma unroll
    for (int c = 0; c < 2; ++c) {
        const int row = c * 32 + srow;
        const int swz = sin ^ ((row & 7) << 4);
        goffA[c] = (size_t)(row0 + row) * (KEFF * 2) + swz;
    }
    #pragma unroll
    for (int c = 0; c < 3; ++c) {
        const int row = c * 32 + srow;
        const int swz = sin ^ ((row & 7) << 4);
        goffB[c] = (size_t)(col0 + row) * (KEFF * 2) + swz;
    }
    const int ldst = tid * 16;
    const char* Abyte = (const char*)A;
    const char* Bbyte = (const char*)Bm;

    f32x4 acc[2][3];
    const f32x4 zf = {0.f, 0.f, 0.f, 0.f};
    #pragma unroll
    for (int m = 0; m < 2; ++m)
        #pragma unroll
        for (int n = 0; n < 3; ++n) acc[m][n] = zf;

    auto stage = [&](int buf, int t) {
        char* la = &lds[buf][0];
        char* lb = &lds[buf][8192];
        const size_t kb = (size_t)t * 128;
        #pragma unroll
        for (int c = 0; c < 2; ++c)
            GLD16(Abyte + goffA[c] + kb, la + c * 4096 + ldst);
        #pragma unroll
        for (int c = 0; c < 3; ++c)
            GLD16(Bbyte + goffB[c] + kb, lb + c * 4096 + ldst);
    };

    const int rl = lane & 15;
    const int kg = lane >> 4;
    const int rswz = (rl & 7) << 4;

    auto compute = [&](int buf) {
        const char* la = &lds[buf][0];
        const char* lb = &lds[buf][8192];
        #pragma unroll
        for (int ks = 0; ks < 2; ++ks) {
            f16x8 av[2], bvv[3];
            #pragma unroll
            for (int m = 0; m < 2; ++m) {
                const int row = wr * 32 + m * 16 + rl;
                const int addr = (row * 128 + ks * 64 + kg * 16) ^ rswz;
                av[m] = *(const f16x8*)(la + addr);
            }
            #pragma unroll
            for (int n = 0; n < 3; ++n) {
                const int row = wc * 48 + n * 16 + rl;
                const int addr = (row * 128 + ks * 64 + kg * 16) ^ rswz;
                bvv[n] = *(const f16x8*)(lb + addr);
            }
            #pragma unroll
            for (int m = 0; m < 2; ++m)
                #pragma unroll
                for (int n = 0; n < 3; ++n)
                    acc[m][n] = __builtin_amdgcn_mfma_f32_16x16x32_f16(
                        av[m], bvv[n], acc[m][n], 0, 0, 0);
        }
    };

    stage(0, 0);
    __syncthreads();
    const int NT = KEFF / 64;   // 8
    for (int t = 0; t < NT; ++t) {
        if (t + 1 < NT) stage((t + 1) & 1, t + 1);
        compute(t & 1);
        __syncthreads();
    }

    // --- epilogue: bias + fp32 store (16-col frag never straddles 512) ---
    #pragma unroll
    for (int n = 0; n < 3; ++n) {
        const int cabs = col0 + wc * 48 + n * 16 + rl;
        const int which = cabs >> 9;
        const int cl = cabs & 511;
        const float* bias = which == 0 ? bq : (which == 1 ? bk : bv);
        float* outp = which == 0 ? qo : (which == 1 ? ko : vo);
        const float bs = bias[cl];
        #pragma unroll
        for (int m = 0; m < 2; ++m) {
            const int rb = row0 + wr * 32 + m * 16 + kg * 4;
            #pragma unroll
            for (int r = 0; r < 4; ++r)
                outp[(size_t)(rb + r) * DIMSZ + cl] = acc[m][n][r] + bs;
        }
    }
}

// ---------------------------------------------------------------------------
// chunk_kv: KV_c[d,e] = sum_j lambda_d^{63-j} k[j,d] v[j,e]   (R3 math)
// ---------------------------------------------------------------------------
__global__ __launch_bounds__(256) void chunk_kv_kernel(
    const float* __restrict__ k, const float* __restrict__ v,
    const float* __restrict__ theta, const float* __restrict__ logamp,
    float2* __restrict__ kv)
{
    const int bhc = blockIdx.x;
    const int c  = bhc & (NC - 1);
    const int bh = bhc >> 4;
    const int b = bh >> 3, h = bh & 7;
    const int tid = threadIdx.x;
    const int lane = tid & 63, grp = tid >> 6;

    __shared__ float ktr[CHUNK][ND + 1];
    __shared__ float kti[CHUNK][ND + 1];
    __shared__ float vs[CHUNK][ND + 1];

    const float th = theta[h*ND + lane];
    const float la = logamp[h];

    for (int jj = 0; jj < 16; ++jj) {
        const int j = grp*16 + jj;
        const int l = c*CHUNK + j;
        const size_t off = ((size_t)(b*L_SEQ + l)) * DIMSZ + h*ND + lane;
        const float kk = k[off];
        const float vv = v[off];
        const float p = (float)(CHUNK - 1 - j);
        const float ap = expf(la * p);
        float s, ct; sincosf(th * p, &s, &ct);
        ktr[j][lane] = kk * ap * ct;
        kti[j][lane] = kk * ap * s;
        vs[j][lane]  = vv;
    }
    __syncthreads();

    float accr[16], acci[16];
    #pragma unroll
    for (int dd = 0; dd < 16; ++dd) { accr[dd] = 0.f; acci[dd] = 0.f; }
    for (int j = 0; j < CHUNK; ++j) {
        const float vv = vs[j][lane];
        #pragma unroll
        for (int dd = 0; dd < 16; ++dd) {
            const int d = grp*16 + dd;
            accr[dd] = fmaf(ktr[j][d], vv, accr[dd]);
            acci[dd] = fmaf(kti[j][d], vv, acci[dd]);
        }
    }
    float2* dst = kv + (size_t)bhc * (ND*ND);
    #pragma unroll
    for (int dd = 0; dd < 16; ++dd) {
        const int d = grp*16 + dd;
        dst[d*ND + lane] = make_float2(accr[dd], acci[dd]);
    }
}

// ---------------------------------------------------------------------------
// scan: B_{c+1} = lambda^64 * B_c + KV_c (complex), B_0 = last_conv.
// kvB[bhc] := state BEFORE chunk c.  Loads prefetched before the chain.
// ---------------------------------------------------------------------------
__global__ __launch_bounds__(256) void scan_kernel(
    float2* __restrict__ kvB,
    const float* __restrict__ lc_re, const float* __restrict__ lc_im,
    const float* __restrict__ theta, const float* __restrict__ logamp)
{
    const int gid = blockIdx.x * 256 + threadIdx.x;   // 65536
    const int bh = gid >> 12;
    const int idx = gid & 4095;
    const int h = bh & 7;
    const int d = idx >> 6;

    const float th = theta[h*ND + d];
    const float la = logamp[h];
    const float ampC = expf(la * (float)CHUNK);
    float s, ct; sincosf(th * (float)CHUNK, &s, &ct);
    const float aCr = ampC * ct, aCi = ampC * s;

    float2* base = kvB + (size_t)bh * NC * (ND*ND) + idx;
    float2 t[NC];
    #pragma unroll
    for (int c = 0; c < NC; ++c) t[c] = base[(size_t)c * (ND*ND)];

    float Sr = lc_re[h*ND*ND + idx];
    float Si = lc_im[h*ND*ND + idx];
    #pragma unroll
    for (int c = 0; c < NC; ++c) {
        base[(size_t)c * (ND*ND)] = make_float2(Sr, Si);
        const float nr = aCr*Sr - aCi*Si + t[c].x;
        const float ni = aCr*Si + aCi*Sr + t[c].y;
        Sr = nr; Si = ni;
    }
}

// ---------------------------------------------------------------------------
// chunk_out: 512 blocks (bhc*2+half), 32 output rows each; asymmetric K/V
// loads (half 0 loads only rows 0..31).  R3 math; B-tile prefetched to regs
// then staged through KI/VS LDS reuse for the cross term.
// ---------------------------------------------------------------------------
__global__ __launch_bounds__(256) void chunk_out_kernel(
    const float* __restrict__ q, const float* __restrict__ k, const float* __restrict__ v,
    const float2* __restrict__ Bst,
    const float* __restrict__ theta, const float* __restrict__ logamp,
    float* __restrict__ out)
{
    const int half = blockIdx.x & 1;
    const int bhc = blockIdx.x >> 1;
    const int c  = bhc & (NC - 1);
    const int bh = bhc >> 4;
    const int b = bh >> 3, h = bh & 7;
    const int tid = threadIdx.x;
    const int lane = tid & 63, grp = tid >> 6;
    const int ty = tid >> 4, tx = tid & 15;   // 2 rows x 4 cols per thread

    __shared__ float QR[32][ND + 1];
    __shared__ float QI[32][ND + 1];
    __shared__ float KR[CHUNK][ND + 1];   // rows 0..31 reused for SA
    __shared__ float KI[CHUNK][ND + 1];   // later reused for BR
    __shared__ float VS[CHUNK][ND + 1];   // later reused for BI
    __shared__ float cth[ND], sth[ND];

    const float la = logamp[h];
    const int kmax = 32 + half * 32;      // rows of K/V this block needs

    // early B-tile loads into registers (latency hidden under scores/PV)
    float2 breg[16];
    const float2* Bbase = Bst + (size_t)bhc * (ND*ND);
    #pragma unroll
    for (int ii = 0; ii < 16; ++ii) breg[ii] = Bbase[tid * 16 + ii];

    const float th = theta[h*ND + lane];
    if (tid < ND) { float s0, c0; sincosf(th, &s0, &c0); cth[tid] = c0; sth[tid] = s0; }
    #pragma unroll
    for (int jj = 0; jj < 8; ++jj) {
        const int jl = grp*8 + jj;
        const int jabs = half*32 + jl;
        const size_t off = ((size_t)(b*L_SEQ + c*CHUNK + jabs)) * DIMSZ + h*ND + lane;
        const float qq = q[off];
        float s, cc; sincosf(th * (float)jabs, &s, &cc);
        QR[jl][lane] = qq * cc; QI[jl][lane] = qq * s;
    }
    const int rpg = kmax >> 2;   // 8 or 16 rows per 64-lane group
    for (int jj = 0; jj < rpg; ++jj) {
        const int j = grp*rpg + jj;
        const size_t off = ((size_t)(b*L_SEQ + c*CHUNK + j)) * DIMSZ + h*ND + lane;
        const float kk = k[off], vv = v[off];
        float s, cc; sincosf(th * (float)j, &s, &cc);
        KR[j][lane] = kk * cc; KI[j][lane] = kk * s;
        VS[j][lane] = vv;
    }
    __syncthreads();

    // ---- intra scores A[jl, jp] = Re(q^ conj(k^)) = qr*kr + qi*ki ----
    // (for half 0, jp >= 32 reads stale LDS; those lanes' results are
    //  discarded by the delta<0 branch below -- never multiplied.)
    float accA[2][4] = {};
    for (int d = 0; d < ND; ++d) {
        float qrv[2], qiv[2], krv[4], kiv[4];
        #pragma unroll
        for (int i = 0; i < 2; ++i) { qrv[i] = QR[ty*2+i][d]; qiv[i] = QI[ty*2+i][d]; }
        #pragma unroll
        for (int u = 0; u < 4; ++u) { krv[u] = KR[tx*4+u][d]; kiv[u] = KI[tx*4+u][d]; }
        #pragma unroll
        for (int i = 0; i < 2; ++i)
            #pragma unroll
            for (int u = 0; u < 4; ++u)
                accA[i][u] = fmaf(qrv[i], krv[u], fmaf(qiv[i], kiv[u], accA[i][u]));
    }
    __syncthreads();

    float (*SA)[ND + 1] = KR;   // rows 0..31
    #pragma unroll
    for (int i = 0; i < 2; ++i) {
        const int jl = ty*2 + i;
        const int jabs = half*32 + jl;
        #pragma unroll
        for (int u = 0; u < 4; ++u) {
            const int jp = tx*4 + u;
            const int delta = jabs - jp;
            SA[jl][jp] = (delta >= 0) ? accA[i][u] * expf(la * (float)delta) : 0.0f;
        }
    }
    __syncthreads();

    // ---- PV ----
    float accO[2][4] = {};
    for (int jp = 0; jp < kmax; ++jp) {
        float av[2], vv[4];
        #pragma unroll
        for (int i = 0; i < 2; ++i) av[i] = SA[ty*2+i][jp];
        #pragma unroll
        for (int u = 0; u < 4; ++u) vv[u] = VS[jp][tx*4+u];
        #pragma unroll
        for (int i = 0; i < 2; ++i)
            #pragma unroll
            for (int u = 0; u < 4; ++u)
                accO[i][u] = fmaf(av[i], vv[u], accO[i][u]);
    }
    __syncthreads();

    // ---- stage B into LDS: BR -> KI, BI -> VS ----
    #pragma unroll
    for (int ii = 0; ii < 16; ++ii) {
        const int id2 = tid * 16 + ii;
        const int d = id2 >> 6, e = id2 & 63;
        KI[d][e] = breg[ii].x;
        VS[d][e] = breg[ii].y;
    }
    __syncthreads();

    // ---- cross: accC = Re( (q^ * e^{i theta}) . B ) ----
    float accC[2][4] = {};
    for (int d = 0; d < ND; ++d) {
        const float cd = cth[d], sd = sth[d];
        float brv[4], biv[4];
        #pragma unroll
        for (int u = 0; u < 4; ++u) { brv[u] = KI[d][tx*4+u]; biv[u] = VS[d][tx*4+u]; }
        #pragma unroll
        for (int i = 0; i < 2; ++i) {
            const float qr = QR[ty*2+i][d], qi = QI[ty*2+i][d];
            const float qcr = qr*cd - qi*sd;
            const float qci = qr*sd + qi*cd;
            #pragma unroll
            for (int u = 0; u < 4; ++u)
                accC[i][u] = fmaf(qcr, brv[u], fmaf(-qci, biv[u], accC[i][u]));
        }
    }

    #pragma unroll
    for (int i = 0; i < 2; ++i) {
        const int jabs = half*32 + ty*2 + i;
        const float cs = expf(la * (float)(jabs + 1));   // amp^{j+1}
        const size_t off = ((size_t)(b*L_SEQ + c*CHUNK + jabs)) * DIMSZ + h*ND + tx*4;
        *(float4*)(out + off) = make_float4(
            fmaf(cs, accC[i][0], accO[i][0]), fmaf(cs, accC[i][1], accO[i][1]),
            fmaf(cs, accC[i][2], accO[i][2]), fmaf(cs, accC[i][3], accO[i][3]));
    }
}

// ---------------------------------------------------------------------------
extern "C" void kernel_launch(void* const* d_in, const int* in_sizes, int n_in,
                              void* d_out, int out_size, void* d_ws, size_t ws_size,
                              hipStream_t stream)
{
    const float* x     = (const float*)d_in[0];
    const float* wq_b  = (const float*)d_in[2];
    const float* wk_b  = (const float*)d_in[4];
    const float* wv_b  = (const float*)d_in[6];
    const float* ph_re = (const float*)d_in[7];
    const float* ph_im = (const float*)d_in[8];
    const float* ampl  = (const float*)d_in[9];
    const float* lc_re = (const float*)d_in[10];
    const float* lc_im = (const float*)d_in[11];
    float* out = (float*)d_out;

    char* wsb = (char*)d_ws;
    const size_t MB = 1024 * 1024;
    float* q      = (float*)(wsb + 0);           // 4 MB
    float* k      = (float*)(wsb + 4 * MB);      // 4 MB
    float* v      = (float*)(wsb + 8 * MB);      // 4 MB
    float* theta  = (float*)(wsb + 12 * MB);     // 2 KB
    float* logamp = (float*)(wsb + 12 * MB + 4096);
    unsigned short* Apk = (unsigned short*)(wsb + 13 * MB);  // 2 MB
    unsigned short* Bpk = (unsigned short*)(wsb + 16 * MB);  // 1.5 MB
    float2* kvB   = (float2*)(wsb + 18 * MB);    // 8 MB

    pack_all_kernel<<<1793, 256, 0, stream>>>(
        x, (const float*)d_in[1], (const float*)d_in[3], (const float*)d_in[5],
        ph_re, ph_im, ampl, Apk, Bpk, theta, logamp);
    gemm_kernel<<<dim3(MTOT / BM, NTOT / BN), 256, 0, stream>>>(
        Apk, Bpk, wq_b, wk_b, wv_b, q, k, v);
    chunk_kv_kernel<<<BHTOT * NC, 256, 0, stream>>>(k, v, theta, logamp, kvB);
    scan_kernel<<<(BHTOT * ND * ND) / 256, 256, 0, stream>>>(kvB, lc_re, lc_im, theta, logamp);
    chunk_out_kernel<<<BHTOT * NC * 2, 256, 0, stream>>>(q, k, v, kvB, theta, logamp, out);
}